// Round 1
// baseline (149.037 us; speedup 1.0000x reference)
//
#include <hip/hip_runtime.h>
#include <hip/hip_bf16.h>

#define B_SZ 16384
#define E_SZ 128
#define H_SZ 256
#define A_SZ 20
#define K_SZ 384           // H + E
#define BH   (B_SZ * H_SZ) // 4194304

typedef __attribute__((ext_vector_type(8))) short  short8v;
typedef __attribute__((ext_vector_type(4))) float  f32x4;
typedef __attribute__((ext_vector_type(2))) float  f32x2;
typedef __attribute__((ext_vector_type(4))) unsigned short ushort4v;
typedef __attribute__((ext_vector_type(2))) unsigned short ushort2v;

__device__ __forceinline__ unsigned short f2bf(float f) {
    union { float f; unsigned u; } v; v.f = f;
    unsigned r = v.u + 0x7fffu + ((v.u >> 16) & 1u);   // RNE
    return (unsigned short)(r >> 16);
}

__device__ __forceinline__ float wsum(float v) {
    #pragma unroll
    for (int off = 32; off > 0; off >>= 1) v += __shfl_xor(v, off, 64);
    return v;
}

__device__ __forceinline__ float sigm(float x) { return 1.0f / (1.0f + __expf(-x)); }

// ---------------- Kernel 1: attention + bf16 pack of A1=[h|x1], A2=[h|x2m] ----
__global__ __launch_bounds__(256) void attn_pack(
    const float* __restrict__ x1, const float* __restrict__ x2,
    const float* __restrict__ h,  const float* __restrict__ wa,
    unsigned short* __restrict__ A1, unsigned short* __restrict__ A2)
{
    const int row  = blockIdx.x * 4 + (threadIdx.x >> 6);
    const int lane = threadIdx.x & 63;

    const f32x4 hv   = *(const f32x4*)(h  + (size_t)row * H_SZ + 4 * lane);
    const f32x2 x1v  = *(const f32x2*)(x1 + (size_t)row * E_SZ + 2 * lane);
    const f32x4 wah  = *(const f32x4*)(wa + 4 * lane);
    const f32x2 wax1 = *(const f32x2*)(wa + H_SZ + 2 * lane);
    const f32x2 wax2 = *(const f32x2*)(wa + H_SZ + E_SZ + 2 * lane);

    float base = hv.x * wah.x + hv.y * wah.y + hv.z * wah.z + hv.w * wah.w
               + x1v.x * wax1.x + x1v.y * wax1.y;

    f32x2 xv[A_SZ];
    float sp[A_SZ];
    const float* x2r = x2 + (size_t)row * A_SZ * E_SZ;
    #pragma unroll
    for (int a = 0; a < A_SZ; ++a) {
        xv[a] = *(const f32x2*)(x2r + a * E_SZ + 2 * lane);
        sp[a] = xv[a].x * wax2.x + xv[a].y * wax2.y;
    }

    base = wsum(base);
    #pragma unroll
    for (int a = 0; a < A_SZ; ++a) sp[a] = wsum(sp[a]) + base;

    float mx = sp[0];
    #pragma unroll
    for (int a = 1; a < A_SZ; ++a) mx = fmaxf(mx, sp[a]);
    float s = 0.0f;
    #pragma unroll
    for (int a = 0; a < A_SZ; ++a) { sp[a] = __expf(sp[a] - mx); s += sp[a]; }
    const float inv = 1.0f / s;

    float m0 = 0.0f, m1 = 0.0f;
    #pragma unroll
    for (int a = 0; a < A_SZ; ++a) { m0 += sp[a] * xv[a].x; m1 += sp[a] * xv[a].y; }
    m0 *= inv; m1 *= inv;

    ushort4v hb;
    hb.x = f2bf(hv.x); hb.y = f2bf(hv.y); hb.z = f2bf(hv.z); hb.w = f2bf(hv.w);
    *(ushort4v*)(A1 + (size_t)row * K_SZ + 4 * lane) = hb;
    *(ushort4v*)(A2 + (size_t)row * K_SZ + 4 * lane) = hb;
    ushort2v x1b; x1b.x = f2bf(x1v.x); x1b.y = f2bf(x1v.y);
    *(ushort2v*)(A1 + (size_t)row * K_SZ + H_SZ + 2 * lane) = x1b;
    ushort2v mb; mb.x = f2bf(m0); mb.y = f2bf(m1);
    *(ushort2v*)(A2 + (size_t)row * K_SZ + H_SZ + 2 * lane) = mb;
}

// ---------------- Kernel 2: weight transpose+pack: Wt[g][n][k] bf16 ----------
struct Ptr8 { const float* p[8]; };

__global__ __launch_bounds__(256) void pack_w(Ptr8 ws, unsigned short* __restrict__ Wt)
{
    const int g = blockIdx.z, nt = blockIdx.y, kt = blockIdx.x;
    __shared__ float tile[64][65];
    const float* W = ws.p[g];
    const int c = threadIdx.x & 63, r0 = threadIdx.x >> 6;
    #pragma unroll
    for (int i = 0; i < 16; ++i) {
        int r = r0 + 4 * i;
        tile[r][c] = W[(size_t)(kt * 64 + r) * H_SZ + nt * 64 + c];
    }
    __syncthreads();
    #pragma unroll
    for (int i = 0; i < 16; ++i) {
        int rr = r0 + 4 * i;
        Wt[(size_t)g * 256 * 384 + (size_t)(nt * 64 + rr) * K_SZ + kt * 64 + c] =
            f2bf(tile[c][rr]);
    }
}

__global__ void pack_b(Ptr8 bs, float* __restrict__ bias)
{
    bias[blockIdx.x * 256 + threadIdx.x] = bs.p[blockIdx.x][threadIdx.x];
}

// ---------------- Kernel 3: fused 8-gate GEMM + LSTM epilogue ----------------
// grid (4, 256): nc = col-block (64 of 256 gate cols), rb = row-block (64 rows)
// 8 waves: wave w computes gate g=w (w<4: cell1 from A1, w>=4: cell2 from A2)
__global__ __launch_bounds__(512) void gemm_ep(
    const unsigned short* __restrict__ A1, const unsigned short* __restrict__ A2,
    const unsigned short* __restrict__ Wt, const float* __restrict__ bias,
    const float* __restrict__ c1, const float* __restrict__ c2,
    float* __restrict__ out)
{
    __shared__ float gl[8 * 32 * 64];   // 64 KB, two row-phases
    const int tid = threadIdx.x, w = tid >> 6, lane = tid & 63;
    const int nc = blockIdx.x, rb = blockIdx.y;
    const int row0 = rb * 64, col0 = nc * 64;

    const unsigned short* Ap = (w < 4) ? A1 : A2;
    const unsigned short* Wg = Wt + (size_t)w * 256 * 384;
    const int fr = lane & 15;            // fragment row/col index
    const int kg = (lane >> 4) * 8;      // k sub-offset

    f32x4 acc[4][4];
    #pragma unroll
    for (int mi = 0; mi < 4; ++mi)
        #pragma unroll
        for (int ni = 0; ni < 4; ++ni) acc[mi][ni] = (f32x4){0.f, 0.f, 0.f, 0.f};

    const unsigned short* abase = Ap + (size_t)(row0 + fr) * K_SZ + kg;
    const unsigned short* bbase = Wg + (size_t)(col0 + fr) * K_SZ + kg;

    for (int kk = 0; kk < 12; ++kk) {
        short8v af[4], bf[4];
        #pragma unroll
        for (int mi = 0; mi < 4; ++mi)
            af[mi] = *(const short8v*)(abase + (size_t)mi * 16 * K_SZ + kk * 32);
        #pragma unroll
        for (int ni = 0; ni < 4; ++ni)
            bf[ni] = *(const short8v*)(bbase + (size_t)ni * 16 * K_SZ + kk * 32);
        #pragma unroll
        for (int mi = 0; mi < 4; ++mi)
            #pragma unroll
            for (int ni = 0; ni < 4; ++ni)
                acc[mi][ni] = __builtin_amdgcn_mfma_f32_16x16x32_bf16(
                    af[mi], bf[ni], acc[mi][ni], 0, 0, 0);
    }

    const int m2   = tid >> 4;          // 0..31 epilogue row
    const int nloc = (tid & 15) * 4;    // 0..60 epilogue col

    #pragma unroll
    for (int ph = 0; ph < 2; ++ph) {
        __syncthreads();
        #pragma unroll
        for (int mi = ph * 2; mi < ph * 2 + 2; ++mi)
            #pragma unroll
            for (int ni = 0; ni < 4; ++ni)
                #pragma unroll
                for (int j = 0; j < 4; ++j) {
                    int m = mi * 16 + ((lane >> 4) * 4) + j - ph * 32;
                    gl[(w * 32 + m) * 64 + ni * 16 + fr] = acc[mi][ni][j];
                }
        __syncthreads();

        const int b   = row0 + ph * 32 + m2;
        const int col = col0 + nloc;
        f32x4 G[8], bia[8];
        #pragma unroll
        for (int g = 0; g < 8; ++g) {
            G[g]   = *(const f32x4*)(gl + (g * 32 + m2) * 64 + nloc);
            bia[g] = *(const f32x4*)(bias + g * 256 + col);
        }
        const f32x4 c1v = *(const f32x4*)(c1 + (size_t)b * H_SZ + col);
        const f32x4 c2v = *(const f32x4*)(c2 + (size_t)b * H_SZ + col);
        f32x4 hn, c1o, c2o;
        #pragma unroll
        for (int j = 0; j < 4; ++j) {
            float f1  = sigm(G[0][j] + bia[0][j]);
            float i1  = sigm(G[1][j] + bia[1][j]);
            float c1t = tanhf(G[2][j] + bia[2][j]);
            float o1  = G[3][j] + bia[3][j];
            float f2  = sigm(G[4][j] + bia[4][j]);
            float i2  = sigm(G[5][j] + bia[5][j]);
            float c2t = tanhf(G[6][j] + bia[6][j]);
            float o2  = G[7][j] + bia[7][j];
            float c1n = f1 * c1v[j] + i1 * c1t;
            float c2n = f2 * c2v[j] + i2 * c2t;
            float mo  = fmaxf(o1, o2);
            float e1  = __expf(o1 - mo), e2 = __expf(o2 - mo);
            float g0  = e1 / (e1 + e2);
            hn[j]  = g0 * tanhf(c1n) + (1.0f - g0) * tanhf(c2n);
            c1o[j] = c1n; c2o[j] = c2n;
        }
        const size_t o0 = (size_t)b * H_SZ + col;
        *(f32x4*)(out + o0)          = hn;
        *(f32x4*)(out + BH + o0)     = c1o;
        *(f32x4*)(out + 2 * BH + o0) = c2o;
    }
}

// ---------------- host ----------------
extern "C" void kernel_launch(void* const* d_in, const int* in_sizes, int n_in,
                              void* d_out, int out_size, void* d_ws, size_t ws_size,
                              hipStream_t stream)
{
    const float* x1 = (const float*)d_in[0];
    const float* x2 = (const float*)d_in[1];
    const float* h  = (const float*)d_in[2];
    const float* c1 = (const float*)d_in[3];
    const float* c2 = (const float*)d_in[4];
    const float* wa = (const float*)d_in[21];

    // gate order: 0..3 = cell1 {f,i,c,o}; 4..7 = cell2 {f,i,c,o}
    Ptr8 wptr, bptr;
    wptr.p[0] = (const float*)d_in[5];  wptr.p[1] = (const float*)d_in[9];
    wptr.p[2] = (const float*)d_in[13]; wptr.p[3] = (const float*)d_in[17];
    wptr.p[4] = (const float*)d_in[6];  wptr.p[5] = (const float*)d_in[10];
    wptr.p[6] = (const float*)d_in[14]; wptr.p[7] = (const float*)d_in[18];
    bptr.p[0] = (const float*)d_in[7];  bptr.p[1] = (const float*)d_in[11];
    bptr.p[2] = (const float*)d_in[15]; bptr.p[3] = (const float*)d_in[19];
    bptr.p[4] = (const float*)d_in[8];  bptr.p[5] = (const float*)d_in[12];
    bptr.p[6] = (const float*)d_in[16]; bptr.p[7] = (const float*)d_in[20];

    char* ws = (char*)d_ws;
    unsigned short* A1   = (unsigned short*)(ws);                       // 12.6 MB
    unsigned short* A2   = (unsigned short*)(ws + 12582912);            // 12.6 MB
    unsigned short* Wt   = (unsigned short*)(ws + 25165824);            // 1.6 MB
    float*          bias = (float*)        (ws + 26738688);             // 8 KB

    attn_pack<<<B_SZ / 4, 256, 0, stream>>>(x1, x2, h, wa, A1, A2);
    pack_w<<<dim3(6, 4, 8), 256, 0, stream>>>(wptr, Wt);
    pack_b<<<8, 256, 0, stream>>>(bptr, bias);
    gemm_ep<<<dim3(4, 256), 512, 0, stream>>>(A1, A2, Wt, bias, c1, c2, (float*)d_out);
}

// Round 2
// 116.346 us; speedup vs baseline: 1.2810x; 1.2810x over previous
//
#include <hip/hip_runtime.h>
#include <hip/hip_bf16.h>

#define B_SZ 16384
#define E_SZ 128
#define H_SZ 256
#define A_SZ 20
#define K_SZ 384           // H + E
#define BH   (B_SZ * H_SZ) // 4194304
#define GLP  68            // epilogue exchange pitch (floats): 272B rows, 16B aligned

typedef __attribute__((ext_vector_type(8))) short  short8v;
typedef __attribute__((ext_vector_type(4))) float  f32x4;
typedef __attribute__((ext_vector_type(2))) float  f32x2;
typedef __attribute__((ext_vector_type(4))) unsigned short ushort4v;
typedef __attribute__((ext_vector_type(2))) unsigned short ushort2v;

__device__ __forceinline__ unsigned short f2bf(float f) {
    union { float f; unsigned u; } v; v.f = f;
    unsigned r = v.u + 0x7fffu + ((v.u >> 16) & 1u);   // RNE
    return (unsigned short)(r >> 16);
}

__device__ __forceinline__ float wsum(float v) {
    #pragma unroll
    for (int off = 32; off > 0; off >>= 1) v += __shfl_xor(v, off, 64);
    return v;
}

__device__ __forceinline__ float sigm(float x) { return 1.0f / (1.0f + __expf(-x)); }

// ---------------- Kernel 1: attention + bf16 pack of A1=[h|x1], A2=[h|x2m] ----
__global__ __launch_bounds__(256) void attn_pack(
    const float* __restrict__ x1, const float* __restrict__ x2,
    const float* __restrict__ h,  const float* __restrict__ wa,
    unsigned short* __restrict__ A1, unsigned short* __restrict__ A2)
{
    const int row  = blockIdx.x * 4 + (threadIdx.x >> 6);
    const int lane = threadIdx.x & 63;

    const f32x4 hv   = *(const f32x4*)(h  + (size_t)row * H_SZ + 4 * lane);
    const f32x2 x1v  = *(const f32x2*)(x1 + (size_t)row * E_SZ + 2 * lane);
    const f32x4 wah  = *(const f32x4*)(wa + 4 * lane);
    const f32x2 wax1 = *(const f32x2*)(wa + H_SZ + 2 * lane);
    const f32x2 wax2 = *(const f32x2*)(wa + H_SZ + E_SZ + 2 * lane);

    float base = hv.x * wah.x + hv.y * wah.y + hv.z * wah.z + hv.w * wah.w
               + x1v.x * wax1.x + x1v.y * wax1.y;

    f32x2 xv[A_SZ];
    float sp[A_SZ];
    const float* x2r = x2 + (size_t)row * A_SZ * E_SZ;
    #pragma unroll
    for (int a = 0; a < A_SZ; ++a) {
        xv[a] = *(const f32x2*)(x2r + a * E_SZ + 2 * lane);
        sp[a] = xv[a].x * wax2.x + xv[a].y * wax2.y;
    }

    base = wsum(base);
    #pragma unroll
    for (int a = 0; a < A_SZ; ++a) sp[a] = wsum(sp[a]) + base;

    float mx = sp[0];
    #pragma unroll
    for (int a = 1; a < A_SZ; ++a) mx = fmaxf(mx, sp[a]);
    float s = 0.0f;
    #pragma unroll
    for (int a = 0; a < A_SZ; ++a) { sp[a] = __expf(sp[a] - mx); s += sp[a]; }
    const float inv = 1.0f / s;

    float m0 = 0.0f, m1 = 0.0f;
    #pragma unroll
    for (int a = 0; a < A_SZ; ++a) { m0 += sp[a] * xv[a].x; m1 += sp[a] * xv[a].y; }
    m0 *= inv; m1 *= inv;

    ushort4v hb;
    hb.x = f2bf(hv.x); hb.y = f2bf(hv.y); hb.z = f2bf(hv.z); hb.w = f2bf(hv.w);
    *(ushort4v*)(A1 + (size_t)row * K_SZ + 4 * lane) = hb;
    *(ushort4v*)(A2 + (size_t)row * K_SZ + 4 * lane) = hb;
    ushort2v x1b; x1b.x = f2bf(x1v.x); x1b.y = f2bf(x1v.y);
    *(ushort2v*)(A1 + (size_t)row * K_SZ + H_SZ + 2 * lane) = x1b;
    ushort2v mb; mb.x = f2bf(m0); mb.y = f2bf(m1);
    *(ushort2v*)(A2 + (size_t)row * K_SZ + H_SZ + 2 * lane) = mb;
}

// ---------------- Kernel 2: weight transpose+pack: Wt[g][n][k] bf16 ----------
struct Ptr8 { const float* p[8]; };

__global__ __launch_bounds__(256) void pack_w(Ptr8 ws, unsigned short* __restrict__ Wt)
{
    const int g = blockIdx.z, nt = blockIdx.y, kt = blockIdx.x;
    __shared__ float tile[64][65];
    const float* W = ws.p[g];
    const int c = threadIdx.x & 63, r0 = threadIdx.x >> 6;
    #pragma unroll
    for (int i = 0; i < 16; ++i) {
        int r = r0 + 4 * i;
        tile[r][c] = W[(size_t)(kt * 64 + r) * H_SZ + nt * 64 + c];
    }
    __syncthreads();
    #pragma unroll
    for (int i = 0; i < 16; ++i) {
        int rr = r0 + 4 * i;
        Wt[(size_t)g * 256 * 384 + (size_t)(nt * 64 + rr) * K_SZ + kt * 64 + c] =
            f2bf(tile[c][rr]);
    }
}

__global__ void pack_b(Ptr8 bs, float* __restrict__ bias)
{
    bias[blockIdx.x * 256 + threadIdx.x] = bs.p[blockIdx.x][threadIdx.x];
}

// ---------------- Kernel 3: fused 8-gate GEMM + LSTM epilogue ----------------
// 1D grid 1024, XCD-swizzled -> logical (rb, nc). 8 waves: wave w = gate g
// (w<4: cell1 from A1, w>=4: cell2 from A2). A tiles LDS-staged (dbuf, BK=128)
// via global_load_lds with both-sides XOR swizzle; B (weights) from L2.
__global__ __launch_bounds__(512, 4) void gemm_ep(
    const unsigned short* __restrict__ A1, const unsigned short* __restrict__ A2,
    const unsigned short* __restrict__ Wt, const float* __restrict__ bias,
    const float* __restrict__ c1, const float* __restrict__ c2,
    float* __restrict__ out)
{
    __shared__ char smem[8 * 32 * GLP * 4];   // 69632B: staging (65536) U epilogue
    const int tid = threadIdx.x, w = tid >> 6, lane = tid & 63;

    // XCD-aware swizzle (nwg=1024 % 8 == 0 -> bijective): 4 col-blocks sharing
    // one A row-tile land on the same XCD's L2.
    const int lid = (blockIdx.x & 7) * 128 + (blockIdx.x >> 3);
    const int nc = lid & 3, rb = lid >> 2;
    const int row0 = rb * 64, col0 = nc * 64;

    const int fr = lane & 15;            // fragment row/col index
    const int hi = lane >> 4;            // k sub-group (8 elems = 16B)

    // ---- staging helper: chunk kc (K cols [kc*128, kc*128+128)) into buf ----
    auto stage_chunk = [&](int buf, int kc) {
        #pragma unroll
        for (int cell = 0; cell < 2; ++cell) {
            const unsigned short* Ap = cell ? A2 : A1;
            #pragma unroll
            for (int c = 0; c < 2; ++c) {
                const int r = c * 32 + w * 4 + hi;            // tile row this lane feeds
                const int s = fr ^ (r & 7);                   // inverse-swizzled 16B slot
                const unsigned short* src =
                    Ap + (size_t)(row0 + r) * K_SZ + kc * 128 + s * 8;
                char* dst = smem + buf * 32768 + cell * 16384 + c * 8192 + w * 1024;
                __builtin_amdgcn_global_load_lds(
                    (const __attribute__((address_space(1))) unsigned int*)src,
                    (__attribute__((address_space(3))) unsigned int*)dst, 16, 0, 0);
            }
        }
    };

    f32x4 acc[4][4];
    #pragma unroll
    for (int mi = 0; mi < 4; ++mi)
        #pragma unroll
        for (int ni = 0; ni < 4; ++ni) acc[mi][ni] = (f32x4){0.f, 0.f, 0.f, 0.f};

    const unsigned short* Wg = Wt + (size_t)w * 256 * 384;
    const unsigned short* bbase = Wg + (size_t)(col0 + fr) * K_SZ + hi * 8;
    const char* cellbase0 = smem + (w >> 2) * 16384;

    stage_chunk(0, 0);
    int buf = 0;
    for (int kc = 0; kc < 3; ++kc) {
        __syncthreads();                       // drains staging of chunk kc
        if (kc < 2) stage_chunk(buf ^ 1, kc + 1);   // overlaps with compute below
        const char* tb = cellbase0 + buf * 32768;
        #pragma unroll
        for (int kk = 0; kk < 4; ++kk) {
            short8v bfr[4], afr[4];
            #pragma unroll
            for (int ni = 0; ni < 4; ++ni)
                bfr[ni] = *(const short8v*)(bbase + (size_t)ni * 16 * K_SZ + kc * 128 + kk * 32);
            #pragma unroll
            for (int mi = 0; mi < 4; ++mi) {
                const int byteoff = ((mi * 16 + fr) * 256 + kk * 64 + hi * 16)
                                    ^ ((fr & 7) << 4);
                afr[mi] = *(const short8v*)(tb + byteoff);
            }
            #pragma unroll
            for (int mi = 0; mi < 4; ++mi)
                #pragma unroll
                for (int ni = 0; ni < 4; ++ni)
                    acc[mi][ni] = __builtin_amdgcn_mfma_f32_16x16x32_bf16(
                        afr[mi], bfr[ni], acc[mi][ni], 0, 0, 0);
        }
        buf ^= 1;
    }

    // ---- epilogue: exchange gates through LDS (reuse smem), 2 row-phases ----
    float* gl = (float*)smem;
    const int m2   = tid >> 4;          // 0..31 epilogue row
    const int nloc = (tid & 15) * 4;    // 0..60 epilogue col

    #pragma unroll
    for (int ph = 0; ph < 2; ++ph) {
        __syncthreads();
        #pragma unroll
        for (int mi = ph * 2; mi < ph * 2 + 2; ++mi)
            #pragma unroll
            for (int ni = 0; ni < 4; ++ni)
                #pragma unroll
                for (int j = 0; j < 4; ++j) {
                    int m = mi * 16 + hi * 4 + j - ph * 32;
                    gl[(w * 32 + m) * GLP + ni * 16 + fr] = acc[mi][ni][j];
                }
        __syncthreads();

        const int b   = row0 + ph * 32 + m2;
        const int col = col0 + nloc;
        f32x4 G[8], bia[8];
        #pragma unroll
        for (int g = 0; g < 8; ++g) {
            G[g]   = *(const f32x4*)(gl + (g * 32 + m2) * GLP + nloc);
            bia[g] = *(const f32x4*)(bias + g * 256 + col);
        }
        const f32x4 c1v = *(const f32x4*)(c1 + (size_t)b * H_SZ + col);
        const f32x4 c2v = *(const f32x4*)(c2 + (size_t)b * H_SZ + col);
        f32x4 hn, c1o, c2o;
        #pragma unroll
        for (int j = 0; j < 4; ++j) {
            float f1  = sigm(G[0][j] + bia[0][j]);
            float i1  = sigm(G[1][j] + bia[1][j]);
            float c1t = tanhf(G[2][j] + bia[2][j]);
            float o1  = G[3][j] + bia[3][j];
            float f2  = sigm(G[4][j] + bia[4][j]);
            float i2  = sigm(G[5][j] + bia[5][j]);
            float c2t = tanhf(G[6][j] + bia[6][j]);
            float o2  = G[7][j] + bia[7][j];
            float c1n = f1 * c1v[j] + i1 * c1t;
            float c2n = f2 * c2v[j] + i2 * c2t;
            float mo  = fmaxf(o1, o2);
            float e1  = __expf(o1 - mo), e2 = __expf(o2 - mo);
            float g0  = e1 / (e1 + e2);
            hn[j]  = g0 * tanhf(c1n) + (1.0f - g0) * tanhf(c2n);
            c1o[j] = c1n; c2o[j] = c2n;
        }
        const size_t o0 = (size_t)b * H_SZ + col;
        *(f32x4*)(out + o0)          = hn;
        *(f32x4*)(out + BH + o0)     = c1o;
        *(f32x4*)(out + 2 * BH + o0) = c2o;
    }
}

// ---------------- host ----------------
extern "C" void kernel_launch(void* const* d_in, const int* in_sizes, int n_in,
                              void* d_out, int out_size, void* d_ws, size_t ws_size,
                              hipStream_t stream)
{
    const float* x1 = (const float*)d_in[0];
    const float* x2 = (const float*)d_in[1];
    const float* h  = (const float*)d_in[2];
    const float* c1 = (const float*)d_in[3];
    const float* c2 = (const float*)d_in[4];
    const float* wa = (const float*)d_in[21];

    // gate order: 0..3 = cell1 {f,i,c,o}; 4..7 = cell2 {f,i,c,o}
    Ptr8 wptr, bptr;
    wptr.p[0] = (const float*)d_in[5];  wptr.p[1] = (const float*)d_in[9];
    wptr.p[2] = (const float*)d_in[13]; wptr.p[3] = (const float*)d_in[17];
    wptr.p[4] = (const float*)d_in[6];  wptr.p[5] = (const float*)d_in[10];
    wptr.p[6] = (const float*)d_in[14]; wptr.p[7] = (const float*)d_in[18];
    bptr.p[0] = (const float*)d_in[7];  bptr.p[1] = (const float*)d_in[11];
    bptr.p[2] = (const float*)d_in[15]; bptr.p[3] = (const float*)d_in[19];
    bptr.p[4] = (const float*)d_in[8];  bptr.p[5] = (const float*)d_in[12];
    bptr.p[6] = (const float*)d_in[16]; bptr.p[7] = (const float*)d_in[20];

    char* ws = (char*)d_ws;
    unsigned short* A1   = (unsigned short*)(ws);                       // 12.6 MB
    unsigned short* A2   = (unsigned short*)(ws + 12582912);            // 12.6 MB
    unsigned short* Wt   = (unsigned short*)(ws + 25165824);            // 1.6 MB
    float*          bias = (float*)        (ws + 26738688);             // 8 KB

    attn_pack<<<B_SZ / 4, 256, 0, stream>>>(x1, x2, h, wa, A1, A2);
    pack_w<<<dim3(6, 4, 8), 256, 0, stream>>>(wptr, Wt);
    pack_b<<<8, 256, 0, stream>>>(bptr, bias);
    gemm_ep<<<1024, 512, 0, stream>>>(A1, A2, Wt, bias, c1, c2, (float*)d_out);
}